// Round 11
// baseline (213.454 us; speedup 1.0000x reference)
//
#include <hip/hip_runtime.h>
#include <stdint.h>

#pragma clang fp contract(off)

#define NMS_B 8
#define NMS_N 4096
#define NMS_NW 64       // 64-bit words per suppression row
#define ROIS 256

typedef unsigned long long u64;
typedef unsigned int u32;

__device__ __forceinline__ u64 rdlane_u64(u64 v, int l) {
    u32 lo = (u32)__builtin_amdgcn_readlane((int)(u32)v, l);
    u32 hi = (u32)__builtin_amdgcn_readlane((int)(u32)(v >> 32), l);
    return ((u64)hi << 32) | lo;
}
__device__ __forceinline__ int lds_slot(int e) { return e + (e >> 2); }  // 4-way max bank aliasing

// ---------------------------------------------------------------------------
// K1a: local bitonic sort of 2048-element chunks (R8 version — known-good).
// ---------------------------------------------------------------------------
__global__ __launch_bounds__(512) void nms_sort_local(
        const float* __restrict__ in, u64* __restrict__ keyb) {
    __shared__ u64 sm[2560];                   // slot(2047)=2558, 20.5 KB
    const int b = blockIdx.y, c = blockIdx.x, t = threadIdx.x;
    const int ebase = c * 2048;
    u64 key[4];

    #pragma unroll
    for (int r = 0; r < 4; ++r) {
        int e = ebase + 4 * t + r;
        float s = in[((size_t)b * NMS_N + e) * 5];
        key[r] = ((u64)(~__float_as_uint(s)) << 32) | (u32)e;
    }

    for (int k = 2; k <= 2048; k <<= 1) {
        int j = k >> 1;
        if (j >= 256) {                        // j = 1024,512,256 via LDS
            #pragma unroll
            for (int r = 0; r < 4; ++r) sm[lds_slot(4 * t + r)] = key[r];
            __syncthreads();
            for (; j >= 256; j >>= 1) {
                for (int el = t; el < 2048; el += 512) {
                    int p = el ^ j;
                    if (p > el) {
                        u64 a = sm[lds_slot(el)], cc = sm[lds_slot(p)];
                        bool up = (((ebase + el) & k) == 0);
                        if ((a > cc) == up) { sm[lds_slot(el)] = cc; sm[lds_slot(p)] = a; }
                    }
                }
                __syncthreads();
            }
            #pragma unroll
            for (int r = 0; r < 4; ++r) key[r] = sm[lds_slot(4 * t + r)];
        }
        for (; j >= 4; j >>= 1) {              // cross-lane via shfl_xor
            int d = j >> 2;
            #pragma unroll
            for (int r = 0; r < 4; ++r) {
                int e = ebase + 4 * t + r;
                u64 mine = key[r];
                u64 part = __shfl_xor(mine, d, 64);
                bool up = ((e & k) == 0);
                bool lower = ((e & j) == 0);
                u64 mn = (mine < part) ? mine : part;
                u64 mx = (mine < part) ? part : mine;
                key[r] = (up == lower) ? mn : mx;
            }
        }
        for (; j >= 1; j >>= 1) {              // j in {2,1}: in-thread
            #pragma unroll
            for (int r = 0; r < 4; ++r) {
                int pr = r | j;
                if (((r & j) == 0) && pr < 4) {
                    int e = ebase + 4 * t + r;
                    bool up = ((e & k) == 0);
                    u64 a = key[r], cc = key[pr];
                    if ((a > cc) == up) { key[r] = cc; key[pr] = a; }
                }
            }
        }
    }

    #pragma unroll
    for (int r = 0; r < 4; ++r)
        keyb[(size_t)b * NMS_N + ebase + 4 * t + r] = key[r];
}

// ---------------------------------------------------------------------------
// K1b: merge stage k=4096 + epilogue (R8 version — known-good).
// ---------------------------------------------------------------------------
__global__ __launch_bounds__(1024) void nms_sort_merge(
        const float* __restrict__ in, const u64* __restrict__ keyb,
        u32* __restrict__ sortedIdx, float4* __restrict__ crn,
        float* __restrict__ ha) {
    __shared__ u64 sm[5120];                   // slot(4095)=5118, 41 KB
    const int b = blockIdx.x, t = threadIdx.x;
    u64 key[4];

    #pragma unroll
    for (int r = 0; r < 4; ++r)
        key[r] = keyb[(size_t)b * NMS_N + 4 * t + r];

    {
        const int k = 4096;
        int j = k >> 1;
        #pragma unroll
        for (int r = 0; r < 4; ++r) sm[lds_slot(4 * t + r)] = key[r];
        __syncthreads();
        for (; j >= 256; j >>= 1) {            // 2048,1024,512,256
            for (int e = t; e < NMS_N; e += 1024) {
                int p = e ^ j;
                if (p > e) {
                    u64 a = sm[lds_slot(e)], cc = sm[lds_slot(p)];
                    bool up = ((e & k) == 0);
                    if ((a > cc) == up) { sm[lds_slot(e)] = cc; sm[lds_slot(p)] = a; }
                }
            }
            __syncthreads();
        }
        #pragma unroll
        for (int r = 0; r < 4; ++r) key[r] = sm[lds_slot(4 * t + r)];

        for (; j >= 4; j >>= 1) {
            int d = j >> 2;
            #pragma unroll
            for (int r = 0; r < 4; ++r) {
                int e = 4 * t + r;
                u64 mine = key[r];
                u64 part = __shfl_xor(mine, d, 64);
                bool up = ((e & k) == 0);
                bool lower = ((e & j) == 0);
                u64 mn = (mine < part) ? mine : part;
                u64 mx = (mine < part) ? part : mine;
                key[r] = (up == lower) ? mn : mx;
            }
        }
        for (; j >= 1; j >>= 1) {
            #pragma unroll
            for (int r = 0; r < 4; ++r) {
                int pr = r | j;
                if (((r & j) == 0) && pr < 4) {
                    int e = 4 * t + r;
                    bool up = ((e & k) == 0);
                    u64 a = key[r], cc = key[pr];
                    if ((a > cc) == up) { key[r] = cc; key[pr] = a; }
                }
            }
        }
    }

    #pragma unroll
    for (int r = 0; r < 4; ++r) {
        int e = 4 * t + r;
        u32 orig = (u32)key[r];
        const float* bp = in + ((size_t)b * NMS_N + orig) * 5;
        float x = bp[1], y = bp[2], w = bp[3], h = bp[4];
        float ws_ = floorf(w * 0.5f);
        float hs_ = floorf(h * 0.5f);
        float X1 = x - ws_, Y1 = y - hs_, X2 = x + ws_, Y2 = y + hs_;
        size_t g = (size_t)b * NMS_N + e;
        sortedIdx[g] = orig;
        crn[g] = make_float4(X1, Y1, X2, Y2);
        ha[g] = 0.5f * ((X2 - X1) * (Y2 - Y1));   // exact: area is a small int
    }
}

// ---------------------------------------------------------------------------
// K2: suppression bitmask (R8 trapezoid) + dense near-diagonal extracts:
//  diagw2[b][B][r] (r=0..127) = words (2B,2B+1) of row 128B+r   [rowblk 2B(+1) at wp=B]
//  subdiag[b][B][r] (r=0..63) = word 2B+2 of row 128B+64+r      [rowblk 2B+1 at wp=B+1]
// Both are fully-computed words (all 128 cols of their wp).
// ---------------------------------------------------------------------------
__global__ __launch_bounds__(256) void nms_mask(
        const float4* __restrict__ crn, const float* __restrict__ ha,
        u64* __restrict__ mask, u64* __restrict__ diagw2,
        u64* __restrict__ subdiag) {
    const int b = blockIdx.y;
    const int u = blockIdx.x * 4 + (threadIdx.x >> 6);   // unit id, 0..1055
    const int lane = threadIdx.x & 63;

    int wp = (int)sqrtf((float)u);
    while (wp * (wp + 1) > u) --wp;
    while ((wp + 1) * (wp + 2) <= u) ++wp;
    const int rowblk = u - wp * (wp + 1);                // 0..2*wp+1

    const size_t base = (size_t)b * NMS_N;
    const int c0 = wp * 128 + lane;
    float4 c0c = crn[base + c0];
    float4 c1c = crn[base + c0 + 64];
    float h0 = ha[base + c0];
    float h1 = ha[base + c0 + 64];

    const int rowbase = __builtin_amdgcn_readfirstlane(rowblk * 64);
    const float4* rowc = crn + base + rowbase;
    const float* rowh = ha + base + rowbase;

    u64 w0 = 0, w1 = 0;
    for (int rg = 0; rg < 64; rg += 8) {
        float fx1[8], fy1[8], fx2[8], fy2[8], fha[8];
        #pragma unroll
        for (int q = 0; q < 8; ++q) {                    // uniform -> s_load
            float4 rc = rowc[rg + q];
            fx1[q] = rc.x; fy1[q] = rc.y; fx2[q] = rc.z; fy2[q] = rc.w;
            fha[q] = rowh[rg + q];
        }
        #pragma unroll
        for (int q = 0; q < 8; ++q) {
            float iw0 = fmaxf(fminf(fx2[q], c0c.z) - fmaxf(fx1[q], c0c.x), 0.0f);
            float ih0 = fmaxf(fminf(fy2[q], c0c.w) - fmaxf(fy1[q], c0c.y), 0.0f);
            float in0 = iw0 * ih0;
            bool p0 = in0 > fmaf(-0.5f, in0, fha[q] + h0);

            float iw1 = fmaxf(fminf(fx2[q], c1c.z) - fmaxf(fx1[q], c1c.x), 0.0f);
            float ih1 = fmaxf(fminf(fy2[q], c1c.w) - fmaxf(fy1[q], c1c.y), 0.0f);
            float in1 = iw1 * ih1;
            bool p1 = in1 > fmaf(-0.5f, in1, fha[q] + h1);

            u64 b0 = __ballot(p0);
            u64 b1 = __ballot(p1);
            if (lane == rg + q) { w0 = b0; w1 = b1; }
        }
    }

    ulonglong2 v; v.x = w0; v.y = w1;
    *(ulonglong2*)&mask[(base + rowbase + lane) * NMS_NW + wp * 2] = v;

    if (rowblk == 2 * wp || rowblk == 2 * wp + 1) {      // diagonal unit
        int r = ((rowblk & 1) << 6) + lane;
        *(ulonglong2*)&diagw2[(((size_t)b * 32 + wp) * 128 + r) * 2] = v;
    }
    if (rowblk == 2 * wp - 1)                            // first sub-diagonal
        subdiag[((size_t)b * 32 + (wp - 1)) * 64 + lane] = w0;
}

// ---------------------------------------------------------------------------
// K3 v7: zero dependent loads on the critical path.
// Per-lane S = suppression word `lane`. Per window W (64 rows, block B=W/2):
//   avail = ~(rdlane(S,W) | carry)   -- carry = reg-only patch from window
//                                       W-1's keeps (validated v5 'dy' trick)
//   ctz loop: keep r -> avail &= ~rdlane(inreg,r); carry' |= rdlane(cross,r)
//     inreg/cross from dense-prefetched diag regs:
//       W=2B:  inreg=dA.x (word 2B),   cross=dA.y (word 2B+1)
//       W=2B+1:inreg=dB.y (word 2B+1), cross=dSb  (word 2B+2, subdiag)
//   flush of window-W keeps (full 512B rows) is DEFERRED: loads issued at
//   end of W, OR'd into S at top of W+2 -- one full window of slack hides
//   the cold-miss latency that cost v4/v6 59us.
// Garbage in unwritten below-diagonal words only reaches S-lanes < W.
// Kept bits in registers (lane = window); v6 epilogue (validated R10).
// ---------------------------------------------------------------------------
__global__ __launch_bounds__(64, 1) void nms_scan(
        const float* __restrict__ in, const u64* __restrict__ mask,
        const u64* __restrict__ diagw2, const u64* __restrict__ subdiag,
        const u32* __restrict__ sortedIdx, float* __restrict__ outp) {
    const int b = blockIdx.x, lane = threadIdx.x;
    const u64* M = mask + (size_t)b * NMS_N * NMS_NW;
    const u64* D = diagw2 + (size_t)b * 32 * 128 * 2;
    const u64* SD = subdiag + (size_t)b * 32 * 64;

    u64 S = 0, mykept = 0, carry = 0;
    int count = 0;

    u64 pendE[16], pendO[16];
    #pragma unroll
    for (int q = 0; q < 16; ++q) { pendE[q] = 0; pendO[q] = 0; }

    // block 0 diag regs
    ulonglong2 dA = *(const ulonglong2*)&D[(size_t)lane * 2];
    ulonglong2 dB = *(const ulonglong2*)&D[(size_t)(64 + lane) * 2];
    u64 dSb = SD[lane];

#define ISSUE_FLUSH(PEND, KM, WBASE)                                        \
    {                                                                       \
        u64 rem = (KM);                                                     \
        _Pragma("unroll")                                                   \
        for (int q = 0; q < 16; ++q) {                                      \
            if (rem != 0) {                                                 \
                int r = __builtin_ctzll(rem); rem &= rem - 1;               \
                PEND[q] = M[(size_t)((WBASE) + r) * NMS_NW + lane];         \
            } else PEND[q] = 0;                                             \
        }                                                                   \
        while (rem != 0) {        /* rare >16-keep window: synchronous */   \
            int r = __builtin_ctzll(rem); rem &= rem - 1;                   \
            S |= M[(size_t)((WBASE) + r) * NMS_NW + lane];                  \
        }                                                                   \
    }

#define CONSUME(PEND)                                                       \
    S |= (((PEND[0] | PEND[1]) | (PEND[2] | PEND[3])) |                     \
          ((PEND[4] | PEND[5]) | (PEND[6] | PEND[7]))) |                    \
         (((PEND[8] | PEND[9]) | (PEND[10] | PEND[11])) |                   \
          ((PEND[12] | PEND[13]) | (PEND[14] | PEND[15])));

    for (int B = 0; B < 32; ++B) {
        // dense prefetch of next block's diag regs (off critical path)
        ulonglong2 nA, nB; u64 nSb = 0;
        nA.x = nA.y = nB.x = nB.y = 0;
        if (B + 1 < 32) {
            const u64* Dn = D + (size_t)(B + 1) * 256;
            nA = *(const ulonglong2*)&Dn[(size_t)lane * 2];
            nB = *(const ulonglong2*)&Dn[(size_t)(64 + lane) * 2];
            if (B + 1 < 31) nSb = SD[(size_t)(B + 1) * 64 + lane];
        }

        // ---------- window W = 2B ----------
        {
            const int W = 2 * B;
            CONSUME(pendE);                      // flush from window W-2
            u64 avail = ~(rdlane_u64(S, W) | carry);
            u64 km = 0, nc = 0;
            while (avail != 0 && count < ROIS) {
                int r = __builtin_ctzll(avail);
                km |= (1ULL << r);
                ++count;
                avail &= ~(rdlane_u64(dA.x, r) | (1ULL << r));
                nc |= rdlane_u64(dA.y, r);
            }
            if (lane == W) mykept = km;
            if (count >= ROIS) goto done;
            carry = nc;
            ISSUE_FLUSH(pendE, km, W * 64);      // consumed at top of W+2
        }

        // ---------- window W = 2B+1 ----------
        {
            const int W = 2 * B + 1;
            CONSUME(pendO);                      // flush from window W-2
            u64 avail = ~(rdlane_u64(S, W) | carry);
            u64 km = 0, nc = 0;
            while (avail != 0 && count < ROIS) {
                int r = __builtin_ctzll(avail);
                km |= (1ULL << r);
                ++count;
                avail &= ~(rdlane_u64(dB.y, r) | (1ULL << r));
                nc |= rdlane_u64(dSb, r);
            }
            if (lane == W) mykept = km;
            if (count >= ROIS) goto done;
            carry = nc;
            ISSUE_FLUSH(pendO, km, W * 64);
        }

        dA = nA; dB = nB; dSb = nSb;
    }
done:

    // epilogue: register kept-bits -> output (v6 style, validated)
    {
        int cnt = (int)__popcll(mykept);
        int pre = cnt;
        #pragma unroll
        for (int d = 1; d < 64; d <<= 1) {
            int tsum = __shfl_up(pre, d, 64);
            if (lane >= d) pre += tsum;
        }
        pre -= cnt;                              // exclusive prefix over lanes
        u64 bits = mykept;
        int slot = pre;
        while (bits != 0) {
            int r = __builtin_ctzll(bits); bits &= bits - 1;
            if (slot < ROIS) {
                int pos = lane * 64 + r;
                int orig = (int)sortedIdx[(size_t)b * NMS_N + pos];
                const float* bp = in + ((size_t)b * NMS_N + orig) * 5;
                float4 o = make_float4(bp[1], bp[2], bp[3], bp[4]);
                ((float4*)outp)[(size_t)b * ROIS + slot] = o;
            }
            ++slot;
        }
    }
#undef ISSUE_FLUSH
#undef CONSUME
}

extern "C" void kernel_launch(void* const* d_in, const int* in_sizes, int n_in,
                              void* d_out, int out_size, void* d_ws, size_t ws_size,
                              hipStream_t stream) {
    const float* in = (const float*)d_in[0];
    float* out = (float*)d_out;
    char* ws = (char*)d_ws;

    u64* mask = (u64*)ws;                                          // 16 MB
    size_t off = (size_t)NMS_B * NMS_N * NMS_NW * sizeof(u64);
    u32* sortedIdx = (u32*)(ws + off); off += (size_t)NMS_B * NMS_N * 4;
    float4* crn = (float4*)(ws + off); off += (size_t)NMS_B * NMS_N * 16;
    float* ha = (float*)(ws + off);    off += (size_t)NMS_B * NMS_N * 4;
    u64* keyb = (u64*)(ws + off);      off += (size_t)NMS_B * NMS_N * 8;
    u64* diagw2 = (u64*)(ws + off);    off += (size_t)NMS_B * 32 * 128 * 2 * 8;
    u64* subdiag = (u64*)(ws + off);   off += (size_t)NMS_B * 32 * 64 * 8;

    nms_sort_local<<<dim3(2, NMS_B), 512, 0, stream>>>(in, keyb);
    nms_sort_merge<<<NMS_B, 1024, 0, stream>>>(in, keyb, sortedIdx, crn, ha);
    nms_mask<<<dim3(264, NMS_B), 256, 0, stream>>>(crn, ha, mask, diagw2, subdiag);
    nms_scan<<<NMS_B, 64, 0, stream>>>(in, mask, diagw2, subdiag, sortedIdx, out);
}

// Round 12
// 144.843 us; speedup vs baseline: 1.4737x; 1.4737x over previous
//
#include <hip/hip_runtime.h>
#include <stdint.h>

#pragma clang fp contract(off)

#define NMS_B 8
#define NMS_N 4096
#define NMS_NW 64       // 64-bit words per suppression row
#define ROIS 256

typedef unsigned long long u64;
typedef unsigned int u32;

__device__ __forceinline__ u64 rdlane_u64(u64 v, int l) {
    u32 lo = (u32)__builtin_amdgcn_readlane((int)(u32)v, l);
    u32 hi = (u32)__builtin_amdgcn_readlane((int)(u32)(v >> 32), l);
    return ((u64)hi << 32) | lo;
}
__device__ __forceinline__ u64 rdfirst_u64(u64 v) {
    u32 lo = (u32)__builtin_amdgcn_readfirstlane((int)(u32)v);
    u32 hi = (u32)__builtin_amdgcn_readfirstlane((int)(u32)(v >> 32));
    return ((u64)hi << 32) | lo;
}
__device__ __forceinline__ int lds_slot(int e) { return e + (e >> 2); }  // 4-way max bank aliasing

// ---------------------------------------------------------------------------
// K1a: local bitonic sort of 2048-element chunks (2 chunks/batch, 16 blocks,
// 512 thr x 4 elems). key = (~score_bits)<<32 | GLOBAL idx; direction bits
// use global e, so the result is bit-identical to the monolithic bitonic
// after its k=2048 stage. (R8 version — best measured.)
// ---------------------------------------------------------------------------
__global__ __launch_bounds__(512) void nms_sort_local(
        const float* __restrict__ in, u64* __restrict__ keyb) {
    __shared__ u64 sm[2560];                   // slot(2047)=2558, 20.5 KB
    const int b = blockIdx.y, c = blockIdx.x, t = threadIdx.x;
    const int ebase = c * 2048;
    u64 key[4];

    #pragma unroll
    for (int r = 0; r < 4; ++r) {
        int e = ebase + 4 * t + r;
        float s = in[((size_t)b * NMS_N + e) * 5];
        key[r] = ((u64)(~__float_as_uint(s)) << 32) | (u32)e;
    }

    for (int k = 2; k <= 2048; k <<= 1) {
        int j = k >> 1;
        if (j >= 256) {                        // j = 1024,512,256 via LDS
            #pragma unroll
            for (int r = 0; r < 4; ++r) sm[lds_slot(4 * t + r)] = key[r];
            __syncthreads();
            for (; j >= 256; j >>= 1) {
                for (int el = t; el < 2048; el += 512) {
                    int p = el ^ j;
                    if (p > el) {
                        u64 a = sm[lds_slot(el)], cc = sm[lds_slot(p)];
                        bool up = (((ebase + el) & k) == 0);
                        if ((a > cc) == up) { sm[lds_slot(el)] = cc; sm[lds_slot(p)] = a; }
                    }
                }
                __syncthreads();
            }
            #pragma unroll
            for (int r = 0; r < 4; ++r) key[r] = sm[lds_slot(4 * t + r)];
        }
        for (; j >= 4; j >>= 1) {              // cross-lane via shfl_xor
            int d = j >> 2;
            #pragma unroll
            for (int r = 0; r < 4; ++r) {
                int e = ebase + 4 * t + r;
                u64 mine = key[r];
                u64 part = __shfl_xor(mine, d, 64);
                bool up = ((e & k) == 0);
                bool lower = ((e & j) == 0);
                u64 mn = (mine < part) ? mine : part;
                u64 mx = (mine < part) ? part : mine;
                key[r] = (up == lower) ? mn : mx;
            }
        }
        for (; j >= 1; j >>= 1) {              // j in {2,1}: in-thread
            #pragma unroll
            for (int r = 0; r < 4; ++r) {
                int pr = r | j;
                if (((r & j) == 0) && pr < 4) {
                    int e = ebase + 4 * t + r;
                    bool up = ((e & k) == 0);
                    u64 a = key[r], cc = key[pr];
                    if ((a > cc) == up) { key[r] = cc; key[pr] = a; }
                }
            }
        }
    }

    #pragma unroll
    for (int r = 0; r < 4; ++r)
        keyb[(size_t)b * NMS_N + ebase + 4 * t + r] = key[r];
}

// ---------------------------------------------------------------------------
// K1b: merge stage k=4096 only, then epilogue: sorted idx + corners
// (floor(w/2) exactly per reference) + HALF-areas (exact: small even ints).
// (R8 version — best measured.)
// ---------------------------------------------------------------------------
__global__ __launch_bounds__(1024) void nms_sort_merge(
        const float* __restrict__ in, const u64* __restrict__ keyb,
        u32* __restrict__ sortedIdx, float4* __restrict__ crn,
        float* __restrict__ ha) {
    __shared__ u64 sm[5120];                   // slot(4095)=5118, 41 KB
    const int b = blockIdx.x, t = threadIdx.x;
    u64 key[4];

    #pragma unroll
    for (int r = 0; r < 4; ++r)
        key[r] = keyb[(size_t)b * NMS_N + 4 * t + r];

    {
        const int k = 4096;
        int j = k >> 1;
        #pragma unroll
        for (int r = 0; r < 4; ++r) sm[lds_slot(4 * t + r)] = key[r];
        __syncthreads();
        for (; j >= 256; j >>= 1) {            // 2048,1024,512,256
            for (int e = t; e < NMS_N; e += 1024) {
                int p = e ^ j;
                if (p > e) {
                    u64 a = sm[lds_slot(e)], cc = sm[lds_slot(p)];
                    bool up = ((e & k) == 0);
                    if ((a > cc) == up) { sm[lds_slot(e)] = cc; sm[lds_slot(p)] = a; }
                }
            }
            __syncthreads();
        }
        #pragma unroll
        for (int r = 0; r < 4; ++r) key[r] = sm[lds_slot(4 * t + r)];

        for (; j >= 4; j >>= 1) {
            int d = j >> 2;
            #pragma unroll
            for (int r = 0; r < 4; ++r) {
                int e = 4 * t + r;
                u64 mine = key[r];
                u64 part = __shfl_xor(mine, d, 64);
                bool up = ((e & k) == 0);
                bool lower = ((e & j) == 0);
                u64 mn = (mine < part) ? mine : part;
                u64 mx = (mine < part) ? part : mine;
                key[r] = (up == lower) ? mn : mx;
            }
        }
        for (; j >= 1; j >>= 1) {
            #pragma unroll
            for (int r = 0; r < 4; ++r) {
                int pr = r | j;
                if (((r & j) == 0) && pr < 4) {
                    int e = 4 * t + r;
                    bool up = ((e & k) == 0);
                    u64 a = key[r], cc = key[pr];
                    if ((a > cc) == up) { key[r] = cc; key[pr] = a; }
                }
            }
        }
    }

    #pragma unroll
    for (int r = 0; r < 4; ++r) {
        int e = 4 * t + r;
        u32 orig = (u32)key[r];
        const float* bp = in + ((size_t)b * NMS_N + orig) * 5;
        float x = bp[1], y = bp[2], w = bp[3], h = bp[4];
        float ws_ = floorf(w * 0.5f);
        float hs_ = floorf(h * 0.5f);
        float X1 = x - ws_, Y1 = y - hs_, X2 = x + ws_, Y2 = y + hs_;
        size_t g = (size_t)b * NMS_N + e;
        sortedIdx[g] = orig;
        crn[g] = make_float4(X1, Y1, X2, Y2);
        ha[g] = 0.5f * ((X2 - X1) * (Y2 - Y1));   // exact: area is a small int
    }
}

// ---------------------------------------------------------------------------
// K2: suppression bitmask, ballot orientation, equal-work trapezoid grid.
// Diagonal units (rowblk==2wp, 2wp+1) also write the dense diag array
// diagw2[b][wp][r] = words (2wp,2wp+1) of row 128*wp+r — fully computed
// words (all bits valid IoU results). (R8 version — best measured.)
// ---------------------------------------------------------------------------
__global__ __launch_bounds__(256) void nms_mask(
        const float4* __restrict__ crn, const float* __restrict__ ha,
        u64* __restrict__ mask, u64* __restrict__ diagw2) {
    const int b = blockIdx.y;
    const int u = blockIdx.x * 4 + (threadIdx.x >> 6);   // unit id, 0..1055
    const int lane = threadIdx.x & 63;

    int wp = (int)sqrtf((float)u);
    while (wp * (wp + 1) > u) --wp;
    while ((wp + 1) * (wp + 2) <= u) ++wp;
    const int rowblk = u - wp * (wp + 1);                // 0..2*wp+1

    const size_t base = (size_t)b * NMS_N;
    const int c0 = wp * 128 + lane;
    float4 c0c = crn[base + c0];
    float4 c1c = crn[base + c0 + 64];
    float h0 = ha[base + c0];
    float h1 = ha[base + c0 + 64];

    const int rowbase = __builtin_amdgcn_readfirstlane(rowblk * 64);
    const float4* rowc = crn + base + rowbase;
    const float* rowh = ha + base + rowbase;

    u64 w0 = 0, w1 = 0;
    for (int rg = 0; rg < 64; rg += 8) {
        float fx1[8], fy1[8], fx2[8], fy2[8], fha[8];
        #pragma unroll
        for (int q = 0; q < 8; ++q) {                    // uniform -> s_load
            float4 rc = rowc[rg + q];
            fx1[q] = rc.x; fy1[q] = rc.y; fx2[q] = rc.z; fy2[q] = rc.w;
            fha[q] = rowh[rg + q];
        }
        #pragma unroll
        for (int q = 0; q < 8; ++q) {
            float iw0 = fmaxf(fminf(fx2[q], c0c.z) - fmaxf(fx1[q], c0c.x), 0.0f);
            float ih0 = fmaxf(fminf(fy2[q], c0c.w) - fmaxf(fy1[q], c0c.y), 0.0f);
            float in0 = iw0 * ih0;
            bool p0 = in0 > fmaf(-0.5f, in0, fha[q] + h0);

            float iw1 = fmaxf(fminf(fx2[q], c1c.z) - fmaxf(fx1[q], c1c.x), 0.0f);
            float ih1 = fmaxf(fminf(fy2[q], c1c.w) - fmaxf(fy1[q], c1c.y), 0.0f);
            float in1 = iw1 * ih1;
            bool p1 = in1 > fmaf(-0.5f, in1, fha[q] + h1);

            u64 b0 = __ballot(p0);
            u64 b1 = __ballot(p1);
            if (lane == rg + q) { w0 = b0; w1 = b1; }
        }
    }

    ulonglong2 v; v.x = w0; v.y = w1;
    *(ulonglong2*)&mask[(base + rowbase + lane) * NMS_NW + wp * 2] = v;

    if (rowblk == 2 * wp || rowblk == 2 * wp + 1) {      // diagonal unit
        int r = ((rowblk & 1) << 6) + lane;              // row offset in 128-window
        *(ulonglong2*)&diagw2[(((size_t)b * 32 + wp) * 128 + r) * 2] = v;
    }
}

// ---------------------------------------------------------------------------
// K3: greedy scan (R8 version — the ONLY fast measured variant, <40 us):
// 64-row windows, stateless curwin gather over kept[] (4-wide + OR-butterfly),
// scalar ctz loop, dense diagw2 prefetch for nextdiag, kept[] in LDS.
// Six alternative structures (incremental-S, LDS pipeline, 128-row windows,
// deferred flush) all measured SLOWER (49-96 us) — do not "improve" this
// without a measured counter-based cause.
// ---------------------------------------------------------------------------
__global__ __launch_bounds__(64, 1) void nms_scan(
        const float* __restrict__ in, const u64* __restrict__ mask,
        const u64* __restrict__ diagw2, const u32* __restrict__ sortedIdx,
        float* __restrict__ outp) {
    const int b = blockIdx.x, lane = threadIdx.x;
    const u64* M = mask + (size_t)b * NMS_N * NMS_NW;
    const u64* D = diagw2 + (size_t)b * 32 * 128 * 2;

    __shared__ int kept[ROIS];
    for (int r = lane; r < ROIS; r += 64) kept[r] = 0;   // safety fallback

    int count = 0;
    // diag for window 0 (rows 0..63, word 0): diagw2 wp=0, h=0
    u64 diag = D[(size_t)lane * 2];

    for (int W = 0; W < 64 && count < ROIS; ++W) {
        // prefetch next window's diagonal from the DENSE array
        u64 nextdiag = 0;
        if (W + 1 < 64) {
            const int Wn = W + 1, Wp = Wn >> 1, h = Wn & 1;
            nextdiag = D[((size_t)Wp * 128 + (h << 6) + lane) * 2 + h];
        }

        // ---- curwin: OR of kept rows' word W ----
        u64 curwin = 0;
        if (count > 0) {
            const int cm1 = count - 1;
            u64 acc = 0;
            #pragma unroll
            for (int s = 0; s < 4; ++s) {                // 4 independent loads
                int j = lane + s * 64;
                int jj = j <= cm1 ? j : cm1;
                int pos = kept[jj];
                u64 v = M[(size_t)pos * NMS_NW + W];
                if (j <= cm1) acc |= v;
            }
            #pragma unroll
            for (int d2 = 1; d2 < 64; d2 <<= 1)          // OR-butterfly
                acc |= (u64)__shfl_xor((long long)acc, d2, 64);
            curwin = rdfirst_u64(acc);
        }

        // ---- serial scalar ctz-skip scan of this window ----
        u64 avail = ~curwin;
        while (avail != 0 && count < ROIS) {
            int r = __builtin_ctzll(avail);
            u64 d = rdlane_u64(diag, r);
            if (lane == 0) kept[count] = W * 64 + r;
            ++count;
            avail &= ~(d | (1ULL << r));
        }

        diag = nextdiag;
    }

    __syncthreads();
    for (int r = lane; r < ROIS; r += 64) {
        int pos = kept[r];
        int orig = (int)sortedIdx[(size_t)b * NMS_N + pos];
        const float* bp = in + ((size_t)b * NMS_N + orig) * 5;
        float4 o = make_float4(bp[1], bp[2], bp[3], bp[4]);
        ((float4*)outp)[(size_t)b * ROIS + r] = o;
    }
}

extern "C" void kernel_launch(void* const* d_in, const int* in_sizes, int n_in,
                              void* d_out, int out_size, void* d_ws, size_t ws_size,
                              hipStream_t stream) {
    const float* in = (const float*)d_in[0];
    float* out = (float*)d_out;
    char* ws = (char*)d_ws;

    u64* mask = (u64*)ws;                                          // 16 MB
    size_t off = (size_t)NMS_B * NMS_N * NMS_NW * sizeof(u64);
    u32* sortedIdx = (u32*)(ws + off); off += (size_t)NMS_B * NMS_N * 4;
    float4* crn = (float4*)(ws + off); off += (size_t)NMS_B * NMS_N * 16;
    float* ha = (float*)(ws + off);    off += (size_t)NMS_B * NMS_N * 4;
    u64* keyb = (u64*)(ws + off);      off += (size_t)NMS_B * NMS_N * 8;
    u64* diagw2 = (u64*)(ws + off);    off += (size_t)NMS_B * 32 * 128 * 2 * 8;

    nms_sort_local<<<dim3(2, NMS_B), 512, 0, stream>>>(in, keyb);
    nms_sort_merge<<<NMS_B, 1024, 0, stream>>>(in, keyb, sortedIdx, crn, ha);
    nms_mask<<<dim3(264, NMS_B), 256, 0, stream>>>(crn, ha, mask, diagw2);
    nms_scan<<<NMS_B, 64, 0, stream>>>(in, mask, diagw2, sortedIdx, out);
}